// Round 5
// baseline (218.678 us; speedup 1.0000x reference)
//
#include <hip/hip_runtime.h>
#include <stdint.h>

#define NR 16
#define NC 80
#define NA 8400
#define NB 16
#define KPRE 1024
#define MAXDET 300
#define CONF_T 0.25f
#define IOU_THR 0.45f
#define SEG 525  // NA / 16 keys per histogram/compact segment block

// Robust scalar read: harness passes python ints most likely as int32; fall
// back to float32 reinterpretation if the int pattern is implausible.
__device__ __forceinline__ float read_dim(const void* p) {
  int iv = *(const int*)p;
  return (iv > 0 && iv < (1 << 20)) ? (float)iv : *(const float*)p;
}

__device__ __forceinline__ const float* level_ptr(const float* p0, const float* p1,
                                                  const float* p2, int a, int& HW,
                                                  int& W, float& stride, int& m) {
  if (a < 6400)      { HW = 6400; W = 80; stride = 8.f;  m = a;        return p0; }
  else if (a < 8000) { HW = 1600; W = 40; stride = 16.f; m = a - 6400; return p1; }
  else               { HW = 400;  W = 20; stride = 32.f; m = a - 8000; return p2; }
}

__device__ __forceinline__ uint64_t readlane64(uint64_t v, int lane) {
  uint32_t lo = (uint32_t)__builtin_amdgcn_readlane((int)(uint32_t)v, lane);
  uint32_t hi = (uint32_t)__builtin_amdgcn_readlane((int)(uint32_t)(v >> 32), lane);
  return ((uint64_t)hi << 32) | lo;
}

// ---------------------------------------------------------------- decode ----
// 1 thread per anchor: every channel-plane load is a 256B/wave segment.
// BW-bound at ~77MB/6.3TBps ~ 12-15us (VALU incl. expf is ~3us wave-level).
// Also zeroes the ghist/gcount scratch for the selection kernels (stream-
// ordered before their atomics; workspace is poisoned each iteration).
__global__ __launch_bounds__(64) void k_decode(
    const float* __restrict__ p0, const float* __restrict__ p1,
    const float* __restrict__ p2, const void* __restrict__ hp,
    const void* __restrict__ wp, float4* __restrict__ boxes,
    uint32_t* __restrict__ keys, int* __restrict__ labels,
    uint32_t* __restrict__ gz) {
  int aid = blockIdx.x * 64 + threadIdx.x;  // grid exactly NB*NA
  if (aid < 2 * NB * 256 + 16) gz[aid] = 0;  // ghist1+ghist2+gcount = 8208 u32
  int b = aid / NA, a = aid - b * NA;
  int HW, W, m; float stride;
  const float* p = level_ptr(p0, p1, p2, a, HW, W, stride, m);
  const float* base = p + (size_t)b * (4 * NR + NC) * HW + m;

  // DFL: softmax-expectation over 16 bins, each of 4 dims
  float d[4];
#pragma unroll
  for (int k = 0; k < 4; ++k) {
    const float* bk = base + (size_t)(k * NR) * HW;
    float v[NR]; float mx = -3.4e38f;
#pragma unroll
    for (int r = 0; r < NR; ++r) { v[r] = bk[(size_t)r * HW]; mx = fmaxf(mx, v[r]); }
    float se = 0.f, sn = 0.f;
#pragma unroll
    for (int r = 0; r < NR; ++r) { float e = expf(v[r] - mx); se += e; sn += e * (float)r; }
    d[k] = sn / se * stride;
  }

  // class argmax over 80 channels (raw logits; sigmoid monotone)
  const float* bc = base + (size_t)(4 * NR) * HW;
  float ml = -3.4e38f; int mc = NC;
#pragma unroll 8
  for (int ch = 0; ch < NC; ++ch) {
    float vv = bc[(size_t)ch * HW];
    if (vv > ml) { ml = vv; mc = ch; }
  }

  int y = m / W, x = m - y * W;
  float cx = ((float)x + 0.5f) * stride, cy = ((float)y + 0.5f) * stride;
  float hx = read_dim(wp) - 1.f, hy = read_dim(hp) - 1.f;
  boxes[aid] = make_float4(fminf(fmaxf(cx - d[0], 0.f), hx),
                           fminf(fmaxf(cy - d[1], 0.f), hy),
                           fminf(fmaxf(cx + d[2], 0.f), hx),
                           fminf(fmaxf(cy + d[3], 0.f), hy));
  float smax = 1.f / (1.f + expf(-ml));
  float s = smax > CONF_T ? smax : -1.0f;
  uint32_t bt = __float_as_uint(s);
  keys[aid] = (bt & 0x80000000u) ? ~bt : (bt | 0x80000000u);  // sortable
  labels[aid] = mc;
}

// ---------------- distributed radix threshold + compact (R11 redesign) -----
// R11 lesson: the single-kernel 16-block selcomp ran on 1/16 of the chip
// (~23us: R1 fused selrank 61.6us minus rank part). Rank in k_rank2 is
// ORDER-INDEPENDENT over the compacted set (count of strictly-greater unique
// keys), so compaction doesn't need per-image ordering -> split across 256
// blocks with global-atomic histograms / slot counters. Threshold arithmetic
// (b1, rem, t16) is integer-exact identical to the old selcomp.

// pass 1: per-segment hist of key>>24 into ghist1[img][256]
__global__ __launch_bounds__(256) void k_hist1(const uint32_t* __restrict__ keys,
                                               uint32_t* __restrict__ ghist1) {
  __shared__ uint32_t h[4][256];
  int img = blockIdx.y, seg = blockIdx.x, tid = threadIdx.x, w = tid >> 6;
  for (int j = tid; j < 1024; j += 256) ((uint32_t*)h)[j] = 0;
  __syncthreads();
  const uint32_t* kb = keys + (size_t)img * NA + seg * SEG;
  for (int j = tid; j < SEG; j += 256) atomicAdd(&h[w][kb[j] >> 24], 1u);
  __syncthreads();
  uint32_t s = h[0][tid] + h[1][tid] + h[2][tid] + h[3][tid];
  if (s) atomicAdd(&ghist1[img * 256 + tid], s);  // few nonzero bins
}

// pass 2: derive b1 (redundant per block, cheap) then hist (key>>16)&0xFF
// restricted to key>>24==b1 into ghist2[img][256]
__global__ __launch_bounds__(256) void k_hist2(const uint32_t* __restrict__ keys,
                                               const uint32_t* __restrict__ ghist1,
                                               uint32_t* __restrict__ ghist2) {
  __shared__ uint32_t hs[256];
  __shared__ uint32_t h[4][256];
  __shared__ int s_b1;
  int img = blockIdx.y, seg = blockIdx.x, tid = threadIdx.x, w = tid >> 6;
  hs[tid] = ghist1[img * 256 + tid];
  for (int j = tid; j < 1024; j += 256) ((uint32_t*)h)[j] = 0;
  __syncthreads();
  {  // suffix-sum crossing: ssuf[tid]>=KPRE && ssuf[tid+1]<KPRE (unique tid)
    uint32_t s = 0;
    for (int j = tid; j < 256; ++j) s += hs[j];
    if (s >= KPRE && (s - hs[tid]) < KPRE) s_b1 = tid;
  }
  __syncthreads();
  int b1 = s_b1;
  const uint32_t* kb = keys + (size_t)img * NA + seg * SEG;
  for (int j = tid; j < SEG; j += 256) {
    uint32_t k = kb[j];
    if ((int)(k >> 24) == b1) atomicAdd(&h[w][(k >> 16) & 0xFF], 1u);
  }
  __syncthreads();
  uint32_t s2 = h[0][tid] + h[1][tid] + h[2][tid] + h[3][tid];
  if (s2) atomicAdd(&ghist2[img * 256 + tid], s2);
}

// pass 3: derive b1/rem/t16 (redundant), compact segment with per-wave
// global-atomic slot base on gcount[img]. cmp order is scrambled across
// blocks — harmless (rank is order-independent; keys unique).
__global__ __launch_bounds__(256) void k_compact(const uint32_t* __restrict__ keys,
                                                 const uint32_t* __restrict__ ghist1,
                                                 const uint32_t* __restrict__ ghist2,
                                                 uint64_t* __restrict__ cmp,
                                                 int* __restrict__ gcount) {
  __shared__ uint32_t hs[256];
  __shared__ int s_b1, s_rem, s_t16;
  int img = blockIdx.y, seg = blockIdx.x, tid = threadIdx.x, lane = tid & 63;
  hs[tid] = ghist1[img * 256 + tid];
  __syncthreads();
  {
    uint32_t s = 0;
    for (int j = tid; j < 256; ++j) s += hs[j];
    if (s >= KPRE && (s - hs[tid]) < KPRE) { s_b1 = tid; s_rem = KPRE - (int)(s - hs[tid]); }
  }
  __syncthreads();
  int b1 = s_b1, rem = s_rem;
  __syncthreads();
  hs[tid] = ghist2[img * 256 + tid];
  __syncthreads();
  {
    uint32_t s = 0;
    for (int j = tid; j < 256; ++j) s += hs[j];
    if ((int)s >= rem && (int)(s - hs[tid]) < rem) s_t16 = (b1 << 8) | tid;
  }
  __syncthreads();
  uint32_t t16 = (uint32_t)s_t16;
  const uint32_t* kb = keys + (size_t)img * NA + seg * SEG;
  for (int j0 = 0; j0 < SEG; j0 += 256) {
    int j = j0 + tid;
    uint32_t k = (j < SEG) ? kb[j] : 0;
    bool pass = (j < SEG) && ((k >> 16) >= t16);
    uint64_t mask = __ballot(pass);
    int pre = __popcll(mask & ((1ull << lane) - 1ull));
    int wc = __popcll(mask);
    int base = 0;
    if (lane == 0) base = wc ? atomicAdd(&gcount[img], wc) : 0;
    base = __shfl(base, 0);
    if (pass)
      cmp[(size_t)img * NA + base + pre] =
          ((uint64_t)k << 32) |
          (uint64_t)(0xFFFFFFFFu - (uint32_t)(seg * SEG + j));
  }
}

// ------------------------------------------------- exact rank on top-M set --
// Compacted set == exact top-M keys (upward-closed at bin granularity), so
// local rank == global rank (order-independent: count of greater keys).
__global__ __launch_bounds__(256) void k_rank2(
    const uint64_t* __restrict__ cmp, const int* __restrict__ ccount,
    const float4* __restrict__ boxes, const int* __restrict__ labels,
    float4* __restrict__ selbox, float4* __restrict__ selboff,
    float* __restrict__ selscore, int* __restrict__ sellab) {
  __shared__ uint64_t sk[2048];
  int img = blockIdx.y;
  int M = ccount[img]; if (M > NA) M = NA;
  if (blockIdx.x * 256 >= M) return;  // uniform per block
  int c = blockIdx.x * 256 + threadIdx.x;
  uint64_t kc = (c < M) ? cmp[(size_t)img * NA + c] : 0;
  int rank = 0;
  for (int j0 = 0; j0 < M; j0 += 2048) {
    int nchunk = min(2048, M - j0);
    __syncthreads();
    for (int j = threadIdx.x; j < nchunk; j += 256)
      sk[j] = cmp[(size_t)img * NA + j0 + j];
    __syncthreads();
    if (c < M) {
      int j = 0;
      for (; j + 4 <= nchunk; j += 4) {
        rank += (int)(sk[j] > kc) + (int)(sk[j + 1] > kc) +
                (int)(sk[j + 2] > kc) + (int)(sk[j + 3] > kc);
      }
      for (; j < nchunk; ++j) rank += (int)(sk[j] > kc);
    }
  }
  if (c < M && rank < KPRE) {
    int a = (int)(0xFFFFFFFFu - (uint32_t)kc);
    uint32_t uk = (uint32_t)(kc >> 32);
    uint32_t bits = (uk & 0x80000000u) ? (uk & 0x7FFFFFFFu) : ~uk;
    float s = __uint_as_float(bits);
    int lab = labels[img * NA + a];
    float4 bx = boxes[img * NA + a];
    float off = (float)lab * 4096.0f;  // replicate reference CLS_OFFSET fp math
    int o = img * KPRE + rank;
    selbox[o] = bx;
    selboff[o] = make_float4(bx.x + off, bx.y + off, bx.z + off, bx.w + off);
    selscore[o] = s;
    sellab[o] = lab;
  }
}

// ----------------------------------------------------- IoU suppression bits -
// Output layout TRANSPOSED: rowmask[img][w][i] (w=word 0..15, i=row 0..1023)
// so k_scan's per-chunk staging loads are coalesced.
// Inner loop rotated per wave-quarter: jb = (jj + (w&3)) & 63 keeps the 4
// concurrent bb[] b128 reads on disjoint 4-bank spans -> conflict-free.
// Areas precomputed into sar[] (bit-identical expression; broadcast read).
__global__ __launch_bounds__(256) void k_iou(const float4* __restrict__ selboff,
                                             uint64_t* __restrict__ rowmask) {
  __shared__ float4 bb[KPRE];
  __shared__ float sar[KPRE];
  int img = blockIdx.y;
  for (int j = threadIdx.x; j < KPRE; j += 256) {
    float4 v = selboff[img * KPRE + j];
    bb[j] = v;
    sar[j] = (v.z - v.x) * (v.w - v.y);
  }
  __syncthreads();
  int i = blockIdx.x * 16 + (threadIdx.x & 15);
  int w = threadIdx.x >> 4;
  int rot = w & 3;
  float4 bi = bb[i];
  float ai = sar[i];
  uint64_t bits = 0;
  for (int jj = 0; jj < 64; ++jj) {
    int jb = (jj + rot) & 63;
    int j = w * 64 + jb;
    float4 bj = bb[j];
    float lx = fmaxf(bi.x, bj.x), ly = fmaxf(bi.y, bj.y);
    float rx = fminf(bi.z, bj.z), ry = fminf(bi.w, bj.w);
    float iw = fmaxf(rx - lx, 0.f), ih = fmaxf(ry - ly, 0.f);
    float inter = iw * ih;
    float aj = sar[j];
    float iou = inter / (ai + aj - inter + 1e-7f);
    bits |= (uint64_t)((iou > IOU_THR) && (j != i)) << jb;
  }
  rowmask[(size_t)img * 16384 + (size_t)w * 1024 + i] = bits;
}

// --------------------------- single-wave barrier-free greedy scan (SALU) ----
// R11 WIN (-13.4us): remv update is a fixed 16-trip branchless masked OR
// across all 64 lanes (lane l: word l&15, row-quarter l>>4) — 16 independent
// ds_read_b64 pipeline under counted lgkmcnt, vs R0's serial ffs-walk
// (ds_read -> lgkmcnt(0) -> v_or per kept row). remv value bit-identical.
__global__ __launch_bounds__(64) void k_scan(
    const uint64_t* __restrict__ rowmask, const float4* __restrict__ selbox,
    const float* __restrict__ selscore, const int* __restrict__ sellab,
    float* __restrict__ out) {
  __shared__ float lsc[KPRE];
  __shared__ uint64_t buf[2][16 * 65];  // [w*65+ii], pad avoids bank conflicts
  __shared__ int keepidx[MAXDET];
  int img = blockIdx.x, lane = threadIdx.x;
  int wsel = lane & 15, q = lane >> 4;
  const uint64_t* g = rowmask + (size_t)img * 16384;

  for (int j = lane; j < KPRE; j += 64) lsc[j] = selscore[img * KPRE + j];

  // stage chunk 0
  {
    uint64_t r0[16];
#pragma unroll
    for (int t = 0; t < 16; ++t) r0[t] = g[t * 1024 + lane];
#pragma unroll
    for (int t = 0; t < 16; ++t) buf[0][t * 65 + lane] = r0[t];
  }
  asm volatile("" ::: "memory");

  uint64_t remv = 0;  // distributed: lane l holds partial of word (l&15),
                      // covering kept rows in quarter (l>>4)
  int n = 0;
  for (int c = 0; c < 16; ++c) {
    uint64_t rn[16];
    if (c + 1 < 16) {  // prefetch next chunk (global, overlapped with scan)
#pragma unroll
      for (int t = 0; t < 16; ++t) rn[t] = g[t * 1024 + (c + 1) * 64 + lane];
    }
    const uint64_t* B = buf[c & 1];
    uint64_t m = B[c * 65 + lane];           // self-chunk word of row `lane`
    float sc = lsc[c * 64 + lane];
    uint64_t vmask = __ballot(sc > CONF_T);  // valid (conf-passing) bitmap
    // suppressed word for this chunk = OR of the 4 quarter-partials
    uint64_t cur = readlane64(remv, c) | readlane64(remv, c + 16) |
                   readlane64(remv, c + 32) | readlane64(remv, c + 48);
    uint64_t kmask = 0;
#pragma unroll
    for (int ii = 0; ii < 64; ++ii) {
      if (((vmask >> ii) & 1ull) && !((cur >> ii) & 1ull)) {
        cur |= readlane64(m, ii);
        kmask |= (1ull << ii);
        if (lane == 0 && n < MAXDET) keepidx[n] = c * 64 + ii;
        n++;
      }
    }
    // branchless parallel remv update: 16 independent masked LDS reads/lane
    {
      uint64_t acc = 0;
#pragma unroll
      for (int t = 0; t < 16; ++t) {
        int ii = q * 16 + t;
        uint64_t msk = (uint64_t)0 - ((kmask >> ii) & 1ull);  // kept ? ~0 : 0
        acc |= B[wsel * 65 + ii] & msk;
      }
      remv |= acc;
    }
    // stop: last candidate of chunk invalid => all later invalid (sorted)
    if (!((vmask >> 63) & 1ull) || n >= MAXDET) break;
    if (c + 1 < 16) {
#pragma unroll
      for (int t = 0; t < 16; ++t) buf[(c + 1) & 1][t * 65 + lane] = rn[t];
    }
    asm volatile("" ::: "memory");
  }

  // parallel output pass
  asm volatile("" ::: "memory");
  float* ob = out;                        // (B,300,4)
  float* os = out + NB * MAXDET * 4;      // (B,300)
  float* ol = out + NB * MAXDET * 5;      // labels as float
  float* ov = out + NB * MAXDET * 6;      // valid as 0/1 float
  int nk = n < MAXDET ? n : MAXDET;
  for (int s0 = 0; s0 < MAXDET; s0 += 64) {
    int slot = s0 + lane;
    if (slot >= MAXDET) break;
    bool v = slot < nk;
    float4 bx = make_float4(0.f, 0.f, 0.f, 0.f);
    float scv = 0.f, lbv = -1.f;
    if (v) {
      int i = keepidx[slot];
      bx = selbox[img * KPRE + i];
      scv = lsc[i];
      lbv = (float)sellab[img * KPRE + i];
    }
    ((float4*)ob)[img * MAXDET + slot] = bx;
    os[img * MAXDET + slot] = scv;
    ol[img * MAXDET + slot] = lbv;
    ov[img * MAXDET + slot] = v ? 1.0f : 0.0f;
  }
}

// -------------------------------------------------------------- launcher ----
extern "C" void kernel_launch(void* const* d_in, const int* in_sizes, int n_in,
                              void* d_out, int out_size, void* d_ws, size_t ws_size,
                              hipStream_t stream) {
  const float* p0 = (const float*)d_in[0];
  const float* p1 = (const float*)d_in[1];
  const float* p2 = (const float*)d_in[2];
  const void* hp = d_in[3];
  const void* wp = d_in[4];

  // Workspace (~5.0 MB). rowmask ALIASES boxes: boxes is dead after
  // k_rank2's gather; k_iou (writer of rowmask) runs strictly after.
  char* ws = (char*)d_ws;
  float4*   boxes    = (float4*)(ws + 0);          // 2150400
  uint64_t* rowmask  = (uint64_t*)(ws + 0);        // alias: 2097152
  uint32_t* keys     = (uint32_t*)(ws + 2150400);  // 537600
  int*      labels   = (int*)(ws + 2688000);       // 537600
  float4*   selbox   = (float4*)(ws + 3225600);    // 262144
  float4*   selboff  = (float4*)(ws + 3487744);    // 262144
  float*    selscore = (float*)(ws + 3749888);     // 65536
  int*      sellab   = (int*)(ws + 3815424);       // 65536
  uint64_t* cmp      = (uint64_t*)(ws + 3881024);  // 1075200 -> 4956224
  uint32_t* ghist1   = (uint32_t*)(ws + 4956224);  // 16384
  uint32_t* ghist2   = (uint32_t*)(ws + 4972608);  // 16384
  int*      gcount   = (int*)(ws + 4988992);       // 64 -> end 4989056
  uint32_t* gz       = (uint32_t*)(ws + 4956224);  // zero region: 8208 u32

  k_decode<<<(NB * NA) / 64, 64, 0, stream>>>(p0, p1, p2, hp, wp,
                                              boxes, keys, labels, gz);
  dim3 sg(16, NB);
  k_hist1<<<sg, 256, 0, stream>>>(keys, ghist1);
  k_hist2<<<sg, 256, 0, stream>>>(keys, ghist1, ghist2);
  k_compact<<<sg, 256, 0, stream>>>(keys, ghist1, ghist2, cmp, gcount);
  dim3 rg((NA + 255) / 256, NB);
  k_rank2<<<rg, 256, 0, stream>>>(cmp, gcount, boxes, labels,
                                  selbox, selboff, selscore, sellab);
  dim3 ig(KPRE / 16, NB);
  k_iou<<<ig, 256, 0, stream>>>(selboff, rowmask);
  k_scan<<<NB, 64, 0, stream>>>(rowmask, selbox, selscore, sellab,
                                (float*)d_out);
}

// Round 6
// 186.778 us; speedup vs baseline: 1.1708x; 1.1708x over previous
//
#include <hip/hip_runtime.h>
#include <stdint.h>

#define NR 16
#define NC 80
#define NA 8400
#define NB 16
#define KPRE 1024
#define MAXDET 300
#define CONF_T 0.25f
#define IOU_THR 0.45f

// Robust scalar read: harness passes python ints most likely as int32; fall
// back to float32 reinterpretation if the int pattern is implausible.
__device__ __forceinline__ float read_dim(const void* p) {
  int iv = *(const int*)p;
  return (iv > 0 && iv < (1 << 20)) ? (float)iv : *(const float*)p;
}

__device__ __forceinline__ const float* level_ptr(const float* p0, const float* p1,
                                                  const float* p2, int a, int& HW,
                                                  int& W, float& stride, int& m) {
  if (a < 6400)      { HW = 6400; W = 80; stride = 8.f;  m = a;        return p0; }
  else if (a < 8000) { HW = 1600; W = 40; stride = 16.f; m = a - 6400; return p1; }
  else               { HW = 400;  W = 20; stride = 32.f; m = a - 8000; return p2; }
}

__device__ __forceinline__ uint64_t readlane64(uint64_t v, int lane) {
  uint32_t lo = (uint32_t)__builtin_amdgcn_readlane((int)(uint32_t)v, lane);
  uint32_t hi = (uint32_t)__builtin_amdgcn_readlane((int)(uint32_t)(v >> 32), lane);
  return ((uint64_t)hi << 32) | lo;
}

// ---------------------------------------------------------------- decode ----
// 1 thread per anchor: every channel-plane load is a 256B/wave segment.
// BW-bound at ~77MB/6.3TBps ~ 12-15us. FP order bit-identical to reference.
__global__ __launch_bounds__(64) void k_decode(
    const float* __restrict__ p0, const float* __restrict__ p1,
    const float* __restrict__ p2, const void* __restrict__ hp,
    const void* __restrict__ wp, float4* __restrict__ boxes,
    uint32_t* __restrict__ keys, int* __restrict__ labels) {
  int aid = blockIdx.x * 64 + threadIdx.x;  // grid exactly NB*NA
  int b = aid / NA, a = aid - b * NA;
  int HW, W, m; float stride;
  const float* p = level_ptr(p0, p1, p2, a, HW, W, stride, m);
  const float* base = p + (size_t)b * (4 * NR + NC) * HW + m;

  // DFL: softmax-expectation over 16 bins, each of 4 dims
  float d[4];
#pragma unroll
  for (int k = 0; k < 4; ++k) {
    const float* bk = base + (size_t)(k * NR) * HW;
    float v[NR]; float mx = -3.4e38f;
#pragma unroll
    for (int r = 0; r < NR; ++r) { v[r] = bk[(size_t)r * HW]; mx = fmaxf(mx, v[r]); }
    float se = 0.f, sn = 0.f;
#pragma unroll
    for (int r = 0; r < NR; ++r) { float e = expf(v[r] - mx); se += e; sn += e * (float)r; }
    d[k] = sn / se * stride;
  }

  // class argmax over 80 channels (raw logits; sigmoid monotone)
  const float* bc = base + (size_t)(4 * NR) * HW;
  float ml = -3.4e38f; int mc = NC;
#pragma unroll 8
  for (int ch = 0; ch < NC; ++ch) {
    float vv = bc[(size_t)ch * HW];
    if (vv > ml) { ml = vv; mc = ch; }
  }

  int y = m / W, x = m - y * W;
  float cx = ((float)x + 0.5f) * stride, cy = ((float)y + 0.5f) * stride;
  float hx = read_dim(wp) - 1.f, hy = read_dim(hp) - 1.f;
  boxes[aid] = make_float4(fminf(fmaxf(cx - d[0], 0.f), hx),
                           fminf(fmaxf(cy - d[1], 0.f), hy),
                           fminf(fmaxf(cx + d[2], 0.f), hx),
                           fminf(fmaxf(cy + d[3], 0.f), hy));
  float smax = 1.f / (1.f + expf(-ml));
  float s = smax > CONF_T ? smax : -1.0f;
  uint32_t bt = __float_as_uint(s);
  keys[aid] = (bt & 0x80000000u) ? ~bt : (bt | 0x80000000u);  // sortable
  labels[aid] = mc;
}

// --------------------- single-pass threshold + compact (per img, 16 blk) ----
// R12 lesson: do NOT distribute this across the chip (R5: gcount atomics on
// one shared cacheline + 2 extra dispatches = +23.5us). Keep 16 blocks.
// Simplification: conf-passing keys have key>>16 in [0xBE80, 0xBF7F] exactly
// (s in (0.25,1) -> key in (0xBE800000,0xBF800000)); conf-failing keys are
// 0x407FFFFF (below range). So ONE 256-bin histogram over key>>16 - 0xBE80
// gives t16 directly: t16 = smallest v with count(key>>16 >= v) >= KPRE —
// provably equal to the old byte3-then-byte2 radix result. Fallback when
// in-range mass < KPRE: t16 = 0x407F (what the old code derived for the
// all- -1.0 bin). Deletes one 8400-key atomic pass + one zero/reduce/suffix
// phase + ~5 syncthreads vs the R4 version.
__global__ __launch_bounds__(1024) void k_selcomp(const uint32_t* __restrict__ keys,
                                                  uint64_t* __restrict__ cmp,
                                                  int* __restrict__ ccount) {
  __shared__ __align__(16) uint32_t skeys[NA];  // 33600 B
  __shared__ uint32_t whist[16][256];           // 16 KB, one hist per wave
  __shared__ uint32_t hsum[256];
  __shared__ int s_t16, s_cnt;
  int img = blockIdx.x, tid = threadIdx.x;
  int w = tid >> 6, lane = tid & 63;
  const uint4* kb4 = (const uint4*)(keys + (size_t)img * NA);  // NA/4 = 2100
  for (int j = tid; j < NA / 4; j += 1024) ((uint4*)skeys)[j] = kb4[j];
  if (tid == 0) s_cnt = 0;
  for (int j = tid; j < 16 * 256; j += 1024) ((uint32_t*)whist)[j] = 0;
  __syncthreads();

  // ---- histogram of (key>>16) - 0xBE80 over conf-passing keys ----
  for (int j = tid; j < NA; j += 1024) {
    uint32_t k = skeys[j];
    if (k >= 0xBE800000u) atomicAdd(&whist[w][(k >> 16) - 0xBE80u], 1u);
  }
  __syncthreads();
  if (tid < 256) {
    uint32_t s = 0;
    for (int i = 0; i < 16; ++i) s += whist[i][tid];
    hsum[tid] = s;
  }
  __syncthreads();
  if (tid < 256) {
    uint32_t s = 0;
    for (int j = tid; j < 256; ++j) s += hsum[j];  // suffix sum from tid
    // unique crossing: ssuf[tid] >= KPRE && ssuf[tid+1] < KPRE
    if (s >= KPRE && (s - hsum[tid]) < KPRE) s_t16 = 0xBE80 + tid;
    if (tid == 0 && s < KPRE) s_t16 = 0x407F;  // fallback: sub-conf bin
  }
  __syncthreads();
  uint32_t t16 = (uint32_t)s_t16;

  // ---- compact: wave-aggregated slot assignment via one LDS atomic/wave ----
  for (int j0 = 0; j0 < NA; j0 += 1024) {
    int j = j0 + tid;
    uint32_t k = (j < NA) ? skeys[j] : 0;
    bool pass = (j < NA) && ((k >> 16) >= t16);
    uint64_t mask = __ballot(pass);
    int pre = __popcll(mask & ((1ull << lane) - 1ull));
    int wc = __popcll(mask);
    int base = 0;
    if (lane == 0) base = wc ? atomicAdd(&s_cnt, wc) : 0;
    base = __shfl(base, 0);
    if (pass)
      cmp[(size_t)img * NA + base + pre] =
          ((uint64_t)k << 32) | (uint64_t)(0xFFFFFFFFu - (uint32_t)j);
  }
  __syncthreads();
  if (tid == 0) ccount[img] = s_cnt;
}

// ------------------------------------------------- exact rank on top-M set --
// Compacted set == exact top-M keys (upward-closed at bin granularity), so
// local rank == global rank (order-independent: count of greater keys).
__global__ __launch_bounds__(256) void k_rank2(
    const uint64_t* __restrict__ cmp, const int* __restrict__ ccount,
    const float4* __restrict__ boxes, const int* __restrict__ labels,
    float4* __restrict__ selbox, float4* __restrict__ selboff,
    float* __restrict__ selscore, int* __restrict__ sellab) {
  __shared__ uint64_t sk[2048];
  int img = blockIdx.y;
  int M = ccount[img]; if (M > NA) M = NA;
  if (blockIdx.x * 256 >= M) return;  // uniform per block
  int c = blockIdx.x * 256 + threadIdx.x;
  uint64_t kc = (c < M) ? cmp[(size_t)img * NA + c] : 0;
  int rank = 0;
  for (int j0 = 0; j0 < M; j0 += 2048) {
    int nchunk = min(2048, M - j0);
    __syncthreads();
    for (int j = threadIdx.x; j < nchunk; j += 256)
      sk[j] = cmp[(size_t)img * NA + j0 + j];
    __syncthreads();
    if (c < M) {
      int j = 0;
      for (; j + 4 <= nchunk; j += 4) {
        rank += (int)(sk[j] > kc) + (int)(sk[j + 1] > kc) +
                (int)(sk[j + 2] > kc) + (int)(sk[j + 3] > kc);
      }
      for (; j < nchunk; ++j) rank += (int)(sk[j] > kc);
    }
  }
  if (c < M && rank < KPRE) {
    int a = (int)(0xFFFFFFFFu - (uint32_t)kc);
    uint32_t uk = (uint32_t)(kc >> 32);
    uint32_t bits = (uk & 0x80000000u) ? (uk & 0x7FFFFFFFu) : ~uk;
    float s = __uint_as_float(bits);
    int lab = labels[img * NA + a];
    float4 bx = boxes[img * NA + a];
    float off = (float)lab * 4096.0f;  // replicate reference CLS_OFFSET fp math
    int o = img * KPRE + rank;
    selbox[o] = bx;
    selboff[o] = make_float4(bx.x + off, bx.y + off, bx.z + off, bx.w + off);
    selscore[o] = s;
    sellab[o] = lab;
  }
}

// ----------------------------------------------------- IoU suppression bits -
// Output layout TRANSPOSED: rowmask[img][w][i] (w=word 0..15, i=row 0..1023)
// so k_scan's per-chunk staging loads are coalesced.
// Inner loop rotated per wave-quarter: jb = (jj + (w&3)) & 63 keeps the 4
// concurrent bb[] b128 reads on disjoint 4-bank spans -> conflict-free.
// Areas precomputed into sar[] (bit-identical expression; broadcast read).
__global__ __launch_bounds__(256) void k_iou(const float4* __restrict__ selboff,
                                             uint64_t* __restrict__ rowmask) {
  __shared__ float4 bb[KPRE];
  __shared__ float sar[KPRE];
  int img = blockIdx.y;
  for (int j = threadIdx.x; j < KPRE; j += 256) {
    float4 v = selboff[img * KPRE + j];
    bb[j] = v;
    sar[j] = (v.z - v.x) * (v.w - v.y);
  }
  __syncthreads();
  int i = blockIdx.x * 16 + (threadIdx.x & 15);
  int w = threadIdx.x >> 4;
  int rot = w & 3;
  float4 bi = bb[i];
  float ai = sar[i];
  uint64_t bits = 0;
  for (int jj = 0; jj < 64; ++jj) {
    int jb = (jj + rot) & 63;
    int j = w * 64 + jb;
    float4 bj = bb[j];
    float lx = fmaxf(bi.x, bj.x), ly = fmaxf(bi.y, bj.y);
    float rx = fminf(bi.z, bj.z), ry = fminf(bi.w, bj.w);
    float iw = fmaxf(rx - lx, 0.f), ih = fmaxf(ry - ly, 0.f);
    float inter = iw * ih;
    float aj = sar[j];
    float iou = inter / (ai + aj - inter + 1e-7f);
    bits |= (uint64_t)((iou > IOU_THR) && (j != i)) << jb;
  }
  rowmask[(size_t)img * 16384 + (size_t)w * 1024 + i] = bits;
}

// --------------------------- single-wave barrier-free greedy scan (SALU) ----
// R11 WIN (-13.4us): remv update is a fixed 16-trip branchless masked OR
// across all 64 lanes (lane l: word l&15, row-quarter l>>4) — 16 independent
// ds_read_b64 pipeline under counted lgkmcnt, vs R0's serial ffs-walk
// (ds_read -> lgkmcnt(0) -> v_or per kept row). remv value bit-identical.
// Do not re-modify without per-kernel timing evidence (R2 lesson).
__global__ __launch_bounds__(64) void k_scan(
    const uint64_t* __restrict__ rowmask, const float4* __restrict__ selbox,
    const float* __restrict__ selscore, const int* __restrict__ sellab,
    float* __restrict__ out) {
  __shared__ float lsc[KPRE];
  __shared__ uint64_t buf[2][16 * 65];  // [w*65+ii], pad avoids bank conflicts
  __shared__ int keepidx[MAXDET];
  int img = blockIdx.x, lane = threadIdx.x;
  int wsel = lane & 15, q = lane >> 4;
  const uint64_t* g = rowmask + (size_t)img * 16384;

  for (int j = lane; j < KPRE; j += 64) lsc[j] = selscore[img * KPRE + j];

  // stage chunk 0
  {
    uint64_t r0[16];
#pragma unroll
    for (int t = 0; t < 16; ++t) r0[t] = g[t * 1024 + lane];
#pragma unroll
    for (int t = 0; t < 16; ++t) buf[0][t * 65 + lane] = r0[t];
  }
  asm volatile("" ::: "memory");

  uint64_t remv = 0;  // distributed: lane l holds partial of word (l&15),
                      // covering kept rows in quarter (l>>4)
  int n = 0;
  for (int c = 0; c < 16; ++c) {
    uint64_t rn[16];
    if (c + 1 < 16) {  // prefetch next chunk (global, overlapped with scan)
#pragma unroll
      for (int t = 0; t < 16; ++t) rn[t] = g[t * 1024 + (c + 1) * 64 + lane];
    }
    const uint64_t* B = buf[c & 1];
    uint64_t m = B[c * 65 + lane];           // self-chunk word of row `lane`
    float sc = lsc[c * 64 + lane];
    uint64_t vmask = __ballot(sc > CONF_T);  // valid (conf-passing) bitmap
    // suppressed word for this chunk = OR of the 4 quarter-partials
    uint64_t cur = readlane64(remv, c) | readlane64(remv, c + 16) |
                   readlane64(remv, c + 32) | readlane64(remv, c + 48);
    uint64_t kmask = 0;
#pragma unroll
    for (int ii = 0; ii < 64; ++ii) {
      if (((vmask >> ii) & 1ull) && !((cur >> ii) & 1ull)) {
        cur |= readlane64(m, ii);
        kmask |= (1ull << ii);
        if (lane == 0 && n < MAXDET) keepidx[n] = c * 64 + ii;
        n++;
      }
    }
    // branchless parallel remv update: 16 independent masked LDS reads/lane
    {
      uint64_t acc = 0;
#pragma unroll
      for (int t = 0; t < 16; ++t) {
        int ii = q * 16 + t;
        uint64_t msk = (uint64_t)0 - ((kmask >> ii) & 1ull);  // kept ? ~0 : 0
        acc |= B[wsel * 65 + ii] & msk;
      }
      remv |= acc;
    }
    // stop: last candidate of chunk invalid => all later invalid (sorted)
    if (!((vmask >> 63) & 1ull) || n >= MAXDET) break;
    if (c + 1 < 16) {
#pragma unroll
      for (int t = 0; t < 16; ++t) buf[(c + 1) & 1][t * 65 + lane] = rn[t];
    }
    asm volatile("" ::: "memory");
  }

  // parallel output pass
  asm volatile("" ::: "memory");
  float* ob = out;                        // (B,300,4)
  float* os = out + NB * MAXDET * 4;      // (B,300)
  float* ol = out + NB * MAXDET * 5;      // labels as float
  float* ov = out + NB * MAXDET * 6;      // valid as 0/1 float
  int nk = n < MAXDET ? n : MAXDET;
  for (int s0 = 0; s0 < MAXDET; s0 += 64) {
    int slot = s0 + lane;
    if (slot >= MAXDET) break;
    bool v = slot < nk;
    float4 bx = make_float4(0.f, 0.f, 0.f, 0.f);
    float scv = 0.f, lbv = -1.f;
    if (v) {
      int i = keepidx[slot];
      bx = selbox[img * KPRE + i];
      scv = lsc[i];
      lbv = (float)sellab[img * KPRE + i];
    }
    ((float4*)ob)[img * MAXDET + slot] = bx;
    os[img * MAXDET + slot] = scv;
    ol[img * MAXDET + slot] = lbv;
    ov[img * MAXDET + slot] = v ? 1.0f : 0.0f;
  }
}

// -------------------------------------------------------------- launcher ----
extern "C" void kernel_launch(void* const* d_in, const int* in_sizes, int n_in,
                              void* d_out, int out_size, void* d_ws, size_t ws_size,
                              hipStream_t stream) {
  const float* p0 = (const float*)d_in[0];
  const float* p1 = (const float*)d_in[1];
  const float* p2 = (const float*)d_in[2];
  const void* hp = d_in[3];
  const void* wp = d_in[4];

  // Workspace (~4.96 MB). rowmask ALIASES boxes: boxes is dead after
  // k_rank2's gather; k_iou (writer of rowmask) runs strictly after.
  char* ws = (char*)d_ws;
  float4*   boxes    = (float4*)(ws + 0);          // 2150400
  uint64_t* rowmask  = (uint64_t*)(ws + 0);        // alias: 2097152
  uint32_t* keys     = (uint32_t*)(ws + 2150400);  // 537600
  int*      labels   = (int*)(ws + 2688000);       // 537600
  float4*   selbox   = (float4*)(ws + 3225600);    // 262144
  float4*   selboff  = (float4*)(ws + 3487744);    // 262144
  float*    selscore = (float*)(ws + 3749888);     // 65536
  int*      sellab   = (int*)(ws + 3815424);       // 65536
  int*      ccount   = (int*)(ws + 3880960);       // 64
  uint64_t* cmp      = (uint64_t*)(ws + 3881024);  // 1075200 -> end 4956224

  k_decode<<<(NB * NA) / 64, 64, 0, stream>>>(p0, p1, p2, hp, wp,
                                              boxes, keys, labels);
  k_selcomp<<<NB, 1024, 0, stream>>>(keys, cmp, ccount);
  dim3 rg((NA + 255) / 256, NB);
  k_rank2<<<rg, 256, 0, stream>>>(cmp, ccount, boxes, labels,
                                  selbox, selboff, selscore, sellab);
  dim3 ig(KPRE / 16, NB);
  k_iou<<<ig, 256, 0, stream>>>(selboff, rowmask);
  k_scan<<<NB, 64, 0, stream>>>(rowmask, selbox, selscore, sellab,
                                (float*)d_out);
}